// Round 1
// baseline (2139.313 us; speedup 1.0000x reference)
//
#include <hip/hip_runtime.h>
#include <math.h>

#define T_TOT   200704      // 4*224*224 tokens
#define C_DIM   192
#define HEADS   6
#define DH      32
#define WSZ     8
#define NTOK    64          // tokens per window
#define NWIN    3136        // 4*28*28
#define HID     384
#define IMG     224
#define NSIDE   28
#define WPI     784         // windows per image
#define QSCALE  0.17677669529663687f

__device__ __forceinline__ float bf_lo(unsigned u){ return __uint_as_float(u << 16); }
__device__ __forceinline__ float bf_hi(unsigned u){ return __uint_as_float(u & 0xFFFF0000u); }
__device__ __forceinline__ float bf2f(unsigned short s){ return __uint_as_float(((unsigned)s) << 16); }
__device__ __forceinline__ unsigned short f2bf(float f){
    unsigned u = __float_as_uint(f);
    u += 0x7FFFu + ((u >> 16) & 1u);
    return (unsigned short)(u >> 16);
}
__device__ __forceinline__ unsigned pack2(float a, float b){
    return (unsigned)f2bf(a) | ((unsigned)f2bf(b) << 16);
}

// ---------------- K1: LN1 + shift + window partition -> xwin bf16 [t][192]
__global__ void k_ln1_win(const float* __restrict__ x, const float* __restrict__ g,
                          const float* __restrict__ bta, unsigned short* __restrict__ xwin)
{
    int t    = blockIdx.x * 4 + (threadIdx.x >> 6);
    int lane = threadIdx.x & 63;
    int win = t >> 6, n = t & 63;
    int bimg = win / WPI, w2 = win % WPI;
    int wi = w2 / NSIDE, wj = w2 % NSIDE;
    int r = n >> 3, c = n & 7;
    int hs = wi * 8 + r + 4; if (hs >= IMG) hs -= IMG;
    int ws = wj * 8 + c + 4; if (ws >= IMG) ws -= IMG;
    int s = bimg * (IMG*IMG) + hs * IMG + ws;
    const float* xp = x + (size_t)s * C_DIM + lane * 3;
    float v0 = xp[0], v1 = xp[1], v2 = xp[2];
    float sum = v0 + v1 + v2;
    float sq  = v0*v0 + v1*v1 + v2*v2;
    #pragma unroll
    for (int m = 1; m < 64; m <<= 1){ sum += __shfl_xor(sum, m); sq += __shfl_xor(sq, m); }
    float mu = sum * (1.f/192.f);
    float var = sq * (1.f/192.f) - mu*mu;
    float rs = rsqrtf(var + 1e-5f);
    int j = lane * 3;
    unsigned short* op = xwin + (size_t)t * C_DIM + j;
    op[0] = f2bf((v0-mu)*rs*g[j]   + bta[j]);
    op[1] = f2bf((v1-mu)*rs*g[j+1] + bta[j+1]);
    op[2] = f2bf((v2-mu)*rs*g[j+2] + bta[j+2]);
}

// ---------------- K5: LN2 (identity mapping) -> ln2 bf16 [t][192]
__global__ void k_ln2(const float* __restrict__ xin, const float* __restrict__ g,
                      const float* __restrict__ bta, unsigned short* __restrict__ o)
{
    int t    = blockIdx.x * 4 + (threadIdx.x >> 6);
    int lane = threadIdx.x & 63;
    const float* xp = xin + (size_t)t * C_DIM + lane * 3;
    float v0 = xp[0], v1 = xp[1], v2 = xp[2];
    float sum = v0 + v1 + v2;
    float sq  = v0*v0 + v1*v1 + v2*v2;
    #pragma unroll
    for (int m = 1; m < 64; m <<= 1){ sum += __shfl_xor(sum, m); sq += __shfl_xor(sq, m); }
    float mu = sum * (1.f/192.f);
    float var = sq * (1.f/192.f) - mu*mu;
    float rs = rsqrtf(var + 1e-5f);
    int j = lane * 3;
    unsigned short* op = o + (size_t)t * C_DIM + j;
    op[0] = f2bf((v0-mu)*rs*g[j]   + bta[j]);
    op[1] = f2bf((v1-mu)*rs*g[j+1] + bta[j+1]);
    op[2] = f2bf((v2-mu)*rs*g[j+2] + bta[j+2]);
}

// ---------------- shared 64x64-tile GEMM body: C[64x64] = A[64xK]bf16 @ W[KxN]f32
template<int KTOT, int NW>
__device__ __forceinline__ void gemm64(const unsigned short* __restrict__ A,
                                       const float* __restrict__ W,
                                       int t0, int n0, float acc[4][4],
                                       unsigned short* As, float* Ws)
{
    const int tid = threadIdx.x;
    const int tr = tid >> 4, tc = tid & 15;
    #pragma unroll
    for (int i = 0; i < 4; i++)
        #pragma unroll
        for (int j = 0; j < 4; j++) acc[i][j] = 0.f;

    for (int k0 = 0; k0 < KTOT; k0 += 64){
        __syncthreads();
        {
            int kk4 = (tid & 15) * 4;
            int mb  = tid >> 4;
            #pragma unroll
            for (int i = 0; i < 4; i++){
                int m = i * 16 + mb;
                *(uint2*)&As[m*68 + kk4] = *(const uint2*)(A + (size_t)(t0+m)*KTOT + k0 + kk4);
            }
            #pragma unroll
            for (int i = 0; i < 4; i++){
                int kk = i * 16 + mb;
                *(float4*)&Ws[kk*68 + kk4] = *(const float4*)(W + (size_t)(k0+kk)*NW + n0 + kk4);
            }
        }
        __syncthreads();
        #pragma unroll 8
        for (int kk = 0; kk < 64; kk += 2){
            float4 w0 = *(const float4*)&Ws[kk*68     + tc*4];
            float4 w1 = *(const float4*)&Ws[(kk+1)*68 + tc*4];
            #pragma unroll
            for (int i = 0; i < 4; i++){
                unsigned a2 = *(const unsigned*)&As[(tr*4+i)*68 + kk];
                float a0 = bf_lo(a2), a1 = bf_hi(a2);
                acc[i][0] = fmaf(a0, w0.x, fmaf(a1, w1.x, acc[i][0]));
                acc[i][1] = fmaf(a0, w0.y, fmaf(a1, w1.y, acc[i][1]));
                acc[i][2] = fmaf(a0, w0.z, fmaf(a1, w1.z, acc[i][2]));
                acc[i][3] = fmaf(a0, w0.w, fmaf(a1, w1.w, acc[i][3]));
            }
        }
    }
}

// ---------------- K2: QKV GEMM + split/scale -> q,k,v bf16 [win][head][64][32]
__global__ void k_qkv(const unsigned short* __restrict__ xwin, const float* __restrict__ W,
                      const float* __restrict__ bias,
                      unsigned short* __restrict__ q, unsigned short* __restrict__ k,
                      unsigned short* __restrict__ v)
{
    __shared__ unsigned short As[64*68];
    __shared__ float Ws[64*68];
    int t0 = blockIdx.x * 64, n0 = blockIdx.y * 64;
    float acc[4][4];
    gemm64<C_DIM, 3*C_DIM>(xwin, W, t0, n0, acc, As, Ws);

    const int tid = threadIdx.x, tr = tid >> 4, tc = tid & 15;
    int which = n0 / C_DIM;
    unsigned short* dst = (which == 0) ? q : (which == 1) ? k : v;
    int ncol = (n0 % C_DIM) + tc * 4;
    int head = ncol >> 5, d = ncol & 31;
    int win = blockIdx.x;
    float bb[4];
    #pragma unroll
    for (int j = 0; j < 4; j++) bb[j] = bias[n0 + tc*4 + j];
    unsigned short* dp = dst + (size_t)((win*HEADS + head)*NTOK)*DH + d;
    #pragma unroll
    for (int i = 0; i < 4; i++){
        int n = tr*4 + i;
        float o0 = acc[i][0]+bb[0], o1 = acc[i][1]+bb[1], o2 = acc[i][2]+bb[2], o3 = acc[i][3]+bb[3];
        if (which == 0){ o0 *= QSCALE; o1 *= QSCALE; o2 *= QSCALE; o3 *= QSCALE; }
        uint2 pk; pk.x = pack2(o0, o1); pk.y = pack2(o2, o3);
        *(uint2*)(dp + n*DH) = pk;
    }
}

// ---------------- K3: windowed attention, one block per (window, head)
__global__ void k_attn(const unsigned short* __restrict__ q, const unsigned short* __restrict__ k,
                       const unsigned short* __restrict__ v, const float* __restrict__ table,
                       unsigned short* __restrict__ attn_o)
{
    __shared__ unsigned short qs[64*32], ks[64*32], vs[64*32];
    __shared__ float Ps[64*65];
    int wh = blockIdx.x;
    int head = wh % HEADS, win = wh / HEADS;
    size_t base = (size_t)wh * (NTOK*DH);
    int tid = threadIdx.x;
    ((uint4*)qs)[tid] = ((const uint4*)(q + base))[tid];
    ((uint4*)ks)[tid] = ((const uint4*)(k + base))[tid];
    ((uint4*)vs)[tid] = ((const uint4*)(v + base))[tid];
    __syncthreads();

    int n = tid >> 2, qq = tid & 3;
    // preload q row
    float qr[32];
    const uint4* qp = (const uint4*)(qs + n*DH);
    #pragma unroll
    for (int d8 = 0; d8 < 4; d8++){
        uint4 qv = qp[d8];
        qr[d8*8+0]=bf_lo(qv.x); qr[d8*8+1]=bf_hi(qv.x);
        qr[d8*8+2]=bf_lo(qv.y); qr[d8*8+3]=bf_hi(qv.y);
        qr[d8*8+4]=bf_lo(qv.z); qr[d8*8+5]=bf_hi(qv.z);
        qr[d8*8+6]=bf_lo(qv.w); qr[d8*8+7]=bf_hi(qv.w);
    }
    int w2 = win % WPI;
    int wi = w2 / NSIDE, wj = w2 % NSIDE;
    int rn = n >> 3, cn = n & 7;
    int hhn = wi*8 + rn, wwn = wj*8 + cn;
    int labn = ((hhn >= 220) ? 2 : (hhn >= 216) ? 1 : 0) * 3 + ((wwn >= 220) ? 2 : (wwn >= 216) ? 1 : 0);

    float f[16];
    float rmax = -1e30f;
    #pragma unroll
    for (int jj = 0; jj < 16; jj++){
        int m = jj*4 + qq;
        const uint4* kp = (const uint4*)(ks + m*DH);
        float dot = 0.f;
        #pragma unroll
        for (int d8 = 0; d8 < 4; d8++){
            uint4 kv = kp[d8];
            dot = fmaf(qr[d8*8+0], bf_lo(kv.x), dot);
            dot = fmaf(qr[d8*8+1], bf_hi(kv.x), dot);
            dot = fmaf(qr[d8*8+2], bf_lo(kv.y), dot);
            dot = fmaf(qr[d8*8+3], bf_hi(kv.y), dot);
            dot = fmaf(qr[d8*8+4], bf_lo(kv.z), dot);
            dot = fmaf(qr[d8*8+5], bf_hi(kv.z), dot);
            dot = fmaf(qr[d8*8+6], bf_lo(kv.w), dot);
            dot = fmaf(qr[d8*8+7], bf_hi(kv.w), dot);
        }
        int rm = m >> 3, cm = m & 7;
        dot += table[((rn - rm + 7)*15 + (cn - cm + 7)) * HEADS + head];
        int hhm = wi*8 + rm, wwm = wj*8 + cm;
        int labm = ((hhm >= 220) ? 2 : (hhm >= 216) ? 1 : 0) * 3 + ((wwm >= 220) ? 2 : (wwm >= 216) ? 1 : 0);
        if (labm != labn) dot -= 100.f;
        f[jj] = dot;
        rmax = fmaxf(rmax, dot);
    }
    rmax = fmaxf(rmax, __shfl_xor(rmax, 1));
    rmax = fmaxf(rmax, __shfl_xor(rmax, 2));
    float rsum = 0.f;
    #pragma unroll
    for (int jj = 0; jj < 16; jj++){ f[jj] = __expf(f[jj] - rmax); rsum += f[jj]; }
    rsum += __shfl_xor(rsum, 1);
    rsum += __shfl_xor(rsum, 2);
    float inv = 1.f / rsum;
    #pragma unroll
    for (int jj = 0; jj < 16; jj++) Ps[n*65 + jj*4 + qq] = f[jj] * inv;
    __syncthreads();

    // PV: out[n][dbase..dbase+7]
    int dbase = qq * 8;
    float av[8] = {0,0,0,0,0,0,0,0};
    for (int m = 0; m < 64; m++){
        float p = Ps[n*65 + m];
        uint4 vv = *(const uint4*)(vs + m*DH + dbase);
        av[0] = fmaf(p, bf_lo(vv.x), av[0]);
        av[1] = fmaf(p, bf_hi(vv.x), av[1]);
        av[2] = fmaf(p, bf_lo(vv.y), av[2]);
        av[3] = fmaf(p, bf_hi(vv.y), av[3]);
        av[4] = fmaf(p, bf_lo(vv.z), av[4]);
        av[5] = fmaf(p, bf_hi(vv.z), av[5]);
        av[6] = fmaf(p, bf_lo(vv.w), av[6]);
        av[7] = fmaf(p, bf_hi(vv.w), av[7]);
    }
    unsigned short* op = attn_o + (size_t)(win*NTOK + n)*C_DIM + head*DH + dbase;
    uint4 o;
    o.x = pack2(av[0], av[1]); o.y = pack2(av[2], av[3]);
    o.z = pack2(av[4], av[5]); o.w = pack2(av[6], av[7]);
    *(uint4*)op = o;
}

// ---------------- K4: proj GEMM + un-window + un-shift + residual -> d_out f32
__global__ void k_proj(const unsigned short* __restrict__ ain, const float* __restrict__ W,
                       const float* __restrict__ bias, const float* __restrict__ x,
                       float* __restrict__ out)
{
    __shared__ unsigned short As[64*68];
    __shared__ float Ws[64*68];
    int t0 = blockIdx.x * 64, n0 = blockIdx.y * 64;
    float acc[4][4];
    gemm64<C_DIM, C_DIM>(ain, W, t0, n0, acc, As, Ws);

    const int tid = threadIdx.x, tr = tid >> 4, tc = tid & 15;
    int win = blockIdx.x;
    int bimg = win / WPI, w2 = win % WPI;
    int wi = w2 / NSIDE, wj = w2 % NSIDE;
    int col = n0 + tc*4;
    float bb[4];
    #pragma unroll
    for (int j = 0; j < 4; j++) bb[j] = bias[col + j];
    #pragma unroll
    for (int i = 0; i < 4; i++){
        int n = tr*4 + i;
        int r = n >> 3, c = n & 7;
        int hf = wi*8 + r + 4; if (hf >= IMG) hf -= IMG;
        int wf = wj*8 + c + 4; if (wf >= IMG) wf -= IMG;
        size_t s = ((size_t)bimg*(IMG*IMG) + hf*IMG + wf) * C_DIM + col;
        float4 xv = *(const float4*)(x + s);
        float4 o;
        o.x = xv.x + acc[i][0] + bb[0];
        o.y = xv.y + acc[i][1] + bb[1];
        o.z = xv.z + acc[i][2] + bb[2];
        o.w = xv.w + acc[i][3] + bb[3];
        *(float4*)(out + s) = o;
    }
}

// ---------------- K6: fc1 GEMM + exact GELU -> h1 bf16 [t][384]
__global__ void k_fc1(const unsigned short* __restrict__ ain, const float* __restrict__ W,
                      const float* __restrict__ bias, unsigned short* __restrict__ h1)
{
    __shared__ unsigned short As[64*68];
    __shared__ float Ws[64*68];
    int t0 = blockIdx.x * 64, n0 = blockIdx.y * 64;
    float acc[4][4];
    gemm64<C_DIM, HID>(ain, W, t0, n0, acc, As, Ws);

    const int tid = threadIdx.x, tr = tid >> 4, tc = tid & 15;
    int col = n0 + tc*4;
    float bb[4];
    #pragma unroll
    for (int j = 0; j < 4; j++) bb[j] = bias[col + j];
    #pragma unroll
    for (int i = 0; i < 4; i++){
        int n = tr*4 + i;
        unsigned short* op = h1 + (size_t)(t0+n)*HID + col;
        uint2 pk;
        float g0, g1;
        {
            float u = acc[i][0] + bb[0]; g0 = 0.5f*u*(1.f + erff(u*0.70710678118654752f));
            float w = acc[i][1] + bb[1]; g1 = 0.5f*w*(1.f + erff(w*0.70710678118654752f));
            pk.x = pack2(g0, g1);
            u = acc[i][2] + bb[2]; g0 = 0.5f*u*(1.f + erff(u*0.70710678118654752f));
            w = acc[i][3] + bb[3]; g1 = 0.5f*w*(1.f + erff(w*0.70710678118654752f));
            pk.y = pack2(g0, g1);
        }
        *(uint2*)op = pk;
    }
}

// ---------------- K7: fc2 GEMM + final residual add into d_out
__global__ void k_fc2(const unsigned short* __restrict__ ain, const float* __restrict__ W,
                      const float* __restrict__ bias, float* __restrict__ out)
{
    __shared__ unsigned short As[64*68];
    __shared__ float Ws[64*68];
    int t0 = blockIdx.x * 64, n0 = blockIdx.y * 64;
    float acc[4][4];
    gemm64<HID, C_DIM>(ain, W, t0, n0, acc, As, Ws);

    const int tid = threadIdx.x, tr = tid >> 4, tc = tid & 15;
    int col = n0 + tc*4;
    float bb[4];
    #pragma unroll
    for (int j = 0; j < 4; j++) bb[j] = bias[col + j];
    #pragma unroll
    for (int i = 0; i < 4; i++){
        int n = tr*4 + i;
        float* op = out + (size_t)(t0+n)*C_DIM + col;
        float4 o = *(const float4*)op;
        o.x += acc[i][0] + bb[0];
        o.y += acc[i][1] + bb[1];
        o.z += acc[i][2] + bb[2];
        o.w += acc[i][3] + bb[3];
        *(float4*)op = o;
    }
}

extern "C" void kernel_launch(void* const* d_in, const int* in_sizes, int n_in,
                              void* d_out, int out_size, void* d_ws, size_t ws_size,
                              hipStream_t stream)
{
    const float* x       = (const float*)d_in[0];
    const float* n1g     = (const float*)d_in[1];
    const float* n1b     = (const float*)d_in[2];
    const float* qkv_w   = (const float*)d_in[3];
    const float* qkv_b   = (const float*)d_in[4];
    const float* proj_w  = (const float*)d_in[5];
    const float* proj_b  = (const float*)d_in[6];
    const float* rtab    = (const float*)d_in[7];
    const float* n2g     = (const float*)d_in[8];
    const float* n2b     = (const float*)d_in[9];
    const float* fc1_w   = (const float*)d_in[10];
    const float* fc1_b   = (const float*)d_in[11];
    const float* fc2_w   = (const float*)d_in[12];
    const float* fc2_b   = (const float*)d_in[13];
    float* out = (float*)d_out;

    char* wsb = (char*)d_ws;
    const size_t SZ = (size_t)T_TOT * C_DIM * 2;   // 77,070,336 bytes
    unsigned short* xwin = (unsigned short*)(wsb);
    unsigned short* qb   = (unsigned short*)(wsb + SZ);
    unsigned short* kb   = (unsigned short*)(wsb + 2*SZ);
    unsigned short* vb   = (unsigned short*)(wsb + 3*SZ);
    unsigned short* attn_o = xwin;   // reuse after QKV consumed xwin
    unsigned short* ln2  = qb;       // reuse after attention
    unsigned short* h1   = kb;       // spans kb+vb (T*384*2 bytes)

    k_ln1_win<<<T_TOT/4, 256, 0, stream>>>(x, n1g, n1b, xwin);
    k_qkv<<<dim3(NWIN, 9), 256, 0, stream>>>(xwin, qkv_w, qkv_b, qb, kb, vb);
    k_attn<<<NWIN*HEADS, 256, 0, stream>>>(qb, kb, vb, rtab, attn_o);
    k_proj<<<dim3(NWIN, 3), 256, 0, stream>>>(attn_o, proj_w, proj_b, x, out);
    k_ln2<<<T_TOT/4, 256, 0, stream>>>(out, n2g, n2b, ln2);
    k_fc1<<<dim3(NWIN, 6), 256, 0, stream>>>(ln2, fc1_w, fc1_b, h1);
    k_fc2<<<dim3(NWIN, 3), 256, 0, stream>>>(h1, fc2_w, fc2_b, out);
}

// Round 4
// 973.363 us; speedup vs baseline: 2.1979x; 2.1979x over previous
//
#include <hip/hip_runtime.h>
#include <math.h>

#define T_TOT   200704
#define C_DIM   192
#define HEADS   6
#define DH      32
#define NTOK    64
#define NWIN    3136
#define HID     384
#define IMG     224
#define NSIDE   28
#define WPI     784
#define QSCALE  0.17677669529663687f

typedef unsigned short ushortT;
typedef short bf16x8 __attribute__((ext_vector_type(8)));
typedef float f32x4 __attribute__((ext_vector_type(4)));

__device__ __forceinline__ float bf_lo(unsigned u){ return __uint_as_float(u << 16); }
__device__ __forceinline__ float bf_hi(unsigned u){ return __uint_as_float(u & 0xFFFF0000u); }
__device__ __forceinline__ unsigned short f2bf(float f){
    unsigned u = __float_as_uint(f);
    u += 0x7FFFu + ((u >> 16) & 1u);
    return (unsigned short)(u >> 16);
}
__device__ __forceinline__ unsigned pack2(float a, float b){
    return (unsigned)f2bf(a) | ((unsigned)f2bf(b) << 16);
}

// ---------------- weight prep: out[n*K+k] = bf16(in[k*N+n])
__global__ void k_wprep(const float* __restrict__ w, unsigned short* __restrict__ o, int K, int N)
{
    int idx = blockIdx.x * 256 + threadIdx.x;
    if (idx >= K * N) return;
    int n = idx / K, k = idx - n * K;
    o[idx] = f2bf(w[(size_t)k * N + n]);
}

// ---------------- K1: LN1 + shift + window partition -> xwin bf16 [t][192]
__global__ void k_ln1_win(const float* __restrict__ x, const float* __restrict__ g,
                          const float* __restrict__ bta, unsigned short* __restrict__ xwin)
{
    int t    = blockIdx.x * 4 + (threadIdx.x >> 6);
    int lane = threadIdx.x & 63;
    int win = t >> 6, n = t & 63;
    int bimg = win / WPI, w2 = win % WPI;
    int wi = w2 / NSIDE, wj = w2 % NSIDE;
    int r = n >> 3, c = n & 7;
    int hs = wi * 8 + r + 4; if (hs >= IMG) hs -= IMG;
    int ws = wj * 8 + c + 4; if (ws >= IMG) ws -= IMG;
    int s = bimg * (IMG*IMG) + hs * IMG + ws;
    const float* xp = x + (size_t)s * C_DIM + lane * 3;
    float v0 = xp[0], v1 = xp[1], v2 = xp[2];
    float sum = v0 + v1 + v2;
    float sq  = v0*v0 + v1*v1 + v2*v2;
    #pragma unroll
    for (int m = 1; m < 64; m <<= 1){ sum += __shfl_xor(sum, m); sq += __shfl_xor(sq, m); }
    float mu = sum * (1.f/192.f);
    float var = sq * (1.f/192.f) - mu*mu;
    float rs = rsqrtf(var + 1e-5f);
    int j = lane * 3;
    unsigned short* op = xwin + (size_t)t * C_DIM + j;
    op[0] = f2bf((v0-mu)*rs*g[j]   + bta[j]);
    op[1] = f2bf((v1-mu)*rs*g[j+1] + bta[j+1]);
    op[2] = f2bf((v2-mu)*rs*g[j+2] + bta[j+2]);
}

// ---------------- LN2 -> ln2 bf16 [t][192]
__global__ void k_ln2(const float* __restrict__ xin, const float* __restrict__ g,
                      const float* __restrict__ bta, unsigned short* __restrict__ o)
{
    int t    = blockIdx.x * 4 + (threadIdx.x >> 6);
    int lane = threadIdx.x & 63;
    const float* xp = xin + (size_t)t * C_DIM + lane * 3;
    float v0 = xp[0], v1 = xp[1], v2 = xp[2];
    float sum = v0 + v1 + v2;
    float sq  = v0*v0 + v1*v1 + v2*v2;
    #pragma unroll
    for (int m = 1; m < 64; m <<= 1){ sum += __shfl_xor(sum, m); sq += __shfl_xor(sq, m); }
    float mu = sum * (1.f/192.f);
    float var = sq * (1.f/192.f) - mu*mu;
    float rs = rsqrtf(var + 1e-5f);
    int j = lane * 3;
    unsigned short* op = o + (size_t)t * C_DIM + j;
    op[0] = f2bf((v0-mu)*rs*g[j]   + bta[j]);
    op[1] = f2bf((v1-mu)*rs*g[j+1] + bta[j+1]);
    op[2] = f2bf((v2-mu)*rs*g[j+2] + bta[j+2]);
}

// ---------------- MFMA GEMM tile: C[128x64] = A[128xK]bf16 @ Wt[NxK]^T bf16
// 256 threads = 4 waves (2x2). Each wave: 64x32 out = acc[4][2] frags of 16x16.
template<int KTOT>
__device__ __forceinline__ void mfma_tile(const unsigned short* __restrict__ A,
                                          const unsigned short* __restrict__ Wt,
                                          int t0, int n0,
                                          f32x4 acc[4][2],
                                          unsigned short* As, unsigned short* Bs)
{
    const int tid = threadIdx.x;
    const int lane = tid & 63, wid = tid >> 6;
    const int wm = wid >> 1, wn = wid & 1;
    const int lr = lane & 15, lk = (lane >> 4) << 3;
    #pragma unroll
    for (int i = 0; i < 4; i++)
        #pragma unroll
        for (int j = 0; j < 2; j++)
            acc[i][j] = (f32x4){0.f, 0.f, 0.f, 0.f};

    const int arow = tid >> 1, asoff = (tid & 1) << 4;   // each thread: 16 shorts (2x uint4)

    for (int k0 = 0; k0 < KTOT; k0 += 32){
        __syncthreads();
        {
            const unsigned short* ga = A + (size_t)(t0 + arow)*KTOT + k0 + asoff;
            *(uint4*)&As[arow*40 + asoff]     = *(const uint4*)(ga);
            *(uint4*)&As[arow*40 + asoff + 8] = *(const uint4*)(ga + 8);
            if (tid < 128){
                const unsigned short* gb = Wt + (size_t)(n0 + arow)*KTOT + k0 + asoff;
                *(uint4*)&Bs[arow*40 + asoff]     = *(const uint4*)(gb);
                *(uint4*)&Bs[arow*40 + asoff + 8] = *(const uint4*)(gb + 8);
            }
        }
        __syncthreads();
        bf16x8 b0 = *(const bf16x8*)&Bs[(wn*32 +      lr)*40 + lk];
        bf16x8 b1 = *(const bf16x8*)&Bs[(wn*32 + 16 + lr)*40 + lk];
        #pragma unroll
        for (int mf = 0; mf < 4; mf++){
            bf16x8 a = *(const bf16x8*)&As[(wm*64 + mf*16 + lr)*40 + lk];
            acc[mf][0] = __builtin_amdgcn_mfma_f32_16x16x32_bf16(a, b0, acc[mf][0], 0, 0, 0);
            acc[mf][1] = __builtin_amdgcn_mfma_f32_16x16x32_bf16(a, b1, acc[mf][1], 0, 0, 0);
        }
    }
}

// ---------------- K2: QKV GEMM -> q,k,v bf16 [win][head][64][32]
__global__ void k_qkv_m(const unsigned short* __restrict__ xwin, const unsigned short* __restrict__ wt,
                        const float* __restrict__ bias,
                        unsigned short* __restrict__ q, unsigned short* __restrict__ k,
                        unsigned short* __restrict__ v)
{
    __shared__ __align__(16) unsigned short As[128*40];
    __shared__ __align__(16) unsigned short Bs[64*40];
    int n0 = blockIdx.x * 64, t0 = blockIdx.y * 128;
    f32x4 acc[4][2];
    mfma_tile<C_DIM>(xwin, wt, t0, n0, acc, As, Bs);

    const int tid = threadIdx.x, lane = tid & 63, wid = tid >> 6;
    const int wm = wid >> 1, wn = wid & 1, lr = lane & 15;
    int win = blockIdx.y * 2 + wm;
    #pragma unroll
    for (int nf = 0; nf < 2; nf++){
        int c = n0 + wn*32 + nf*16 + lr;
        float b = bias[c];
        int which = c / C_DIM, cc = c % C_DIM;
        unsigned short* dst = (which == 0) ? q : (which == 1) ? k : v;
        float sc = (which == 0) ? QSCALE : 1.f;
        int head = cc >> 5, d = cc & 31;
        unsigned short* dp = dst + ((size_t)(win*HEADS + head) * NTOK) * DH + d;
        #pragma unroll
        for (int mf = 0; mf < 4; mf++){
            #pragma unroll
            for (int r = 0; r < 4; r++){
                int ntok = mf*16 + ((lane >> 4) << 2) + r;
                dp[ntok*DH] = f2bf((acc[mf][nf][r] + b) * sc);
            }
        }
    }
}

// ---------------- K3: windowed attention
__global__ void k_attn(const unsigned short* __restrict__ q, const unsigned short* __restrict__ k,
                       const unsigned short* __restrict__ v, const float* __restrict__ table,
                       unsigned short* __restrict__ attn_o)
{
    __shared__ unsigned short qs[64*32], ks[64*32], vs[64*32];
    __shared__ float Ps[64*65];
    int wh = blockIdx.x;
    int head = wh % HEADS, win = wh / HEADS;
    size_t base = (size_t)wh * (NTOK*DH);
    int tid = threadIdx.x;
    ((uint4*)qs)[tid] = ((const uint4*)(q + base))[tid];
    ((uint4*)ks)[tid] = ((const uint4*)(k + base))[tid];
    ((uint4*)vs)[tid] = ((const uint4*)(v + base))[tid];
    __syncthreads();

    int n = tid >> 2, qq = tid & 3;
    float qr[32];
    const uint4* qp = (const uint4*)(qs + n*DH);
    #pragma unroll
    for (int d8 = 0; d8 < 4; d8++){
        uint4 qv = qp[d8];
        qr[d8*8+0]=bf_lo(qv.x); qr[d8*8+1]=bf_hi(qv.x);
        qr[d8*8+2]=bf_lo(qv.y); qr[d8*8+3]=bf_hi(qv.y);
        qr[d8*8+4]=bf_lo(qv.z); qr[d8*8+5]=bf_hi(qv.z);
        qr[d8*8+6]=bf_lo(qv.w); qr[d8*8+7]=bf_hi(qv.w);
    }
    int w2 = win % WPI;
    int wi = w2 / NSIDE, wj = w2 % NSIDE;
    int rn = n >> 3, cn = n & 7;
    int hhn = wi*8 + rn, wwn = wj*8 + cn;
    int labn = ((hhn >= 220) ? 2 : (hhn >= 216) ? 1 : 0) * 3 + ((wwn >= 220) ? 2 : (wwn >= 216) ? 1 : 0);

    float f[16];
    float rmax = -1e30f;
    #pragma unroll
    for (int jj = 0; jj < 16; jj++){
        int m = jj*4 + qq;
        const uint4* kp = (const uint4*)(ks + m*DH);
        float dot = 0.f;
        #pragma unroll
        for (int d8 = 0; d8 < 4; d8++){
            uint4 kv = kp[d8];
            dot = fmaf(qr[d8*8+0], bf_lo(kv.x), dot);
            dot = fmaf(qr[d8*8+1], bf_hi(kv.x), dot);
            dot = fmaf(qr[d8*8+2], bf_lo(kv.y), dot);
            dot = fmaf(qr[d8*8+3], bf_hi(kv.y), dot);
            dot = fmaf(qr[d8*8+4], bf_lo(kv.z), dot);
            dot = fmaf(qr[d8*8+5], bf_hi(kv.z), dot);
            dot = fmaf(qr[d8*8+6], bf_lo(kv.w), dot);
            dot = fmaf(qr[d8*8+7], bf_hi(kv.w), dot);
        }
        int rm = m >> 3, cm = m & 7;
        dot += table[((rn - rm + 7)*15 + (cn - cm + 7)) * HEADS + head];
        int hhm = wi*8 + rm, wwm = wj*8 + cm;
        int labm = ((hhm >= 220) ? 2 : (hhm >= 216) ? 1 : 0) * 3 + ((wwm >= 220) ? 2 : (wwm >= 216) ? 1 : 0);
        if (labm != labn) dot -= 100.f;
        f[jj] = dot;
        rmax = fmaxf(rmax, dot);
    }
    rmax = fmaxf(rmax, __shfl_xor(rmax, 1));
    rmax = fmaxf(rmax, __shfl_xor(rmax, 2));
    float rsum = 0.f;
    #pragma unroll
    for (int jj = 0; jj < 16; jj++){ f[jj] = __expf(f[jj] - rmax); rsum += f[jj]; }
    rsum += __shfl_xor(rsum, 1);
    rsum += __shfl_xor(rsum, 2);
    float inv = 1.f / rsum;
    #pragma unroll
    for (int jj = 0; jj < 16; jj++) Ps[n*65 + jj*4 + qq] = f[jj] * inv;
    __syncthreads();

    int dbase = qq * 8;
    float av[8] = {0,0,0,0,0,0,0,0};
    for (int m = 0; m < 64; m++){
        float p = Ps[n*65 + m];
        uint4 vv = *(const uint4*)(vs + m*DH + dbase);
        av[0] = fmaf(p, bf_lo(vv.x), av[0]);
        av[1] = fmaf(p, bf_hi(vv.x), av[1]);
        av[2] = fmaf(p, bf_lo(vv.y), av[2]);
        av[3] = fmaf(p, bf_hi(vv.y), av[3]);
        av[4] = fmaf(p, bf_lo(vv.z), av[4]);
        av[5] = fmaf(p, bf_hi(vv.z), av[5]);
        av[6] = fmaf(p, bf_lo(vv.w), av[6]);
        av[7] = fmaf(p, bf_hi(vv.w), av[7]);
    }
    unsigned short* op = attn_o + (size_t)(win*NTOK + n)*C_DIM + head*DH + dbase;
    uint4 o;
    o.x = pack2(av[0], av[1]); o.y = pack2(av[2], av[3]);
    o.z = pack2(av[4], av[5]); o.w = pack2(av[6], av[7]);
    *(uint4*)op = o;
}

// ---------------- K4: proj GEMM + un-window + un-shift + residual -> d_out f32
__global__ void k_proj_m(const unsigned short* __restrict__ ain, const unsigned short* __restrict__ wt,
                         const float* __restrict__ bias, const float* __restrict__ x,
                         float* __restrict__ out)
{
    __shared__ __align__(16) unsigned short As[128*40];
    __shared__ __align__(16) unsigned short Bs[64*40];
    int n0 = blockIdx.x * 64, t0 = blockIdx.y * 128;
    f32x4 acc[4][2];
    mfma_tile<C_DIM>(ain, wt, t0, n0, acc, As, Bs);

    const int tid = threadIdx.x, lane = tid & 63, wid = tid >> 6;
    const int wm = wid >> 1, wn = wid & 1, lr = lane & 15;
    float b0 = bias[n0 + wn*32 + lr];
    float b1 = bias[n0 + wn*32 + 16 + lr];
    #pragma unroll
    for (int mf = 0; mf < 4; mf++){
        #pragma unroll
        for (int r = 0; r < 4; r++){
            int t = t0 + wm*64 + mf*16 + ((lane >> 4) << 2) + r;
            int win = t >> 6, n = t & 63;
            int bimg = win / WPI, w2 = win % WPI;
            int wi = w2 / NSIDE, wj = w2 % NSIDE;
            int rr = n >> 3, cc = n & 7;
            int hf = wi*8 + rr + 4; if (hf >= IMG) hf -= IMG;
            int wf = wj*8 + cc + 4; if (wf >= IMG) wf -= IMG;
            size_t s = ((size_t)bimg*(IMG*IMG) + hf*IMG + wf) * C_DIM;
            int c0 = n0 + wn*32 + lr;
            out[s + c0]      = x[s + c0]      + acc[mf][0][r] + b0;
            out[s + c0 + 16] = x[s + c0 + 16] + acc[mf][1][r] + b1;
        }
    }
}

// ---------------- K6: fc1 GEMM + exact GELU -> h1 bf16 [t][384]
__global__ void k_fc1_m(const unsigned short* __restrict__ ain, const unsigned short* __restrict__ wt,
                        const float* __restrict__ bias, unsigned short* __restrict__ h1)
{
    __shared__ __align__(16) unsigned short As[128*40];
    __shared__ __align__(16) unsigned short Bs[64*40];
    int n0 = blockIdx.x * 64, t0 = blockIdx.y * 128;
    f32x4 acc[4][2];
    mfma_tile<C_DIM>(ain, wt, t0, n0, acc, As, Bs);

    const int tid = threadIdx.x, lane = tid & 63, wid = tid >> 6;
    const int wm = wid >> 1, wn = wid & 1, lr = lane & 15;
    #pragma unroll
    for (int nf = 0; nf < 2; nf++){
        int c = n0 + wn*32 + nf*16 + lr;
        float b = bias[c];
        #pragma unroll
        for (int mf = 0; mf < 4; mf++){
            #pragma unroll
            for (int r = 0; r < 4; r++){
                int t = t0 + wm*64 + mf*16 + ((lane >> 4) << 2) + r;
                float u = acc[mf][nf][r] + b;
                float gl = 0.5f*u*(1.f + erff(u*0.70710678118654752f));
                h1[(size_t)t*HID + c] = f2bf(gl);
            }
        }
    }
}

// ---------------- K7: fc2 GEMM + final residual add into d_out
__global__ void k_fc2_m(const unsigned short* __restrict__ ain, const unsigned short* __restrict__ wt,
                        const float* __restrict__ bias, float* __restrict__ out)
{
    __shared__ __align__(16) unsigned short As[128*40];
    __shared__ __align__(16) unsigned short Bs[64*40];
    int n0 = blockIdx.x * 64, t0 = blockIdx.y * 128;
    f32x4 acc[4][2];
    mfma_tile<HID>(ain, wt, t0, n0, acc, As, Bs);

    const int tid = threadIdx.x, lane = tid & 63, wid = tid >> 6;
    const int wm = wid >> 1, wn = wid & 1, lr = lane & 15;
    #pragma unroll
    for (int nf = 0; nf < 2; nf++){
        int c = n0 + wn*32 + nf*16 + lr;
        float b = bias[c];
        #pragma unroll
        for (int mf = 0; mf < 4; mf++){
            #pragma unroll
            for (int r = 0; r < 4; r++){
                int t = t0 + wm*64 + mf*16 + ((lane >> 4) << 2) + r;
                out[(size_t)t*C_DIM + c] += acc[mf][nf][r] + b;
            }
        }
    }
}

extern "C" void kernel_launch(void* const* d_in, const int* in_sizes, int n_in,
                              void* d_out, int out_size, void* d_ws, size_t ws_size,
                              hipStream_t stream)
{
    const float* x       = (const float*)d_in[0];
    const float* n1g     = (const float*)d_in[1];
    const float* n1b     = (const float*)d_in[2];
    const float* qkv_w   = (const float*)d_in[3];
    const float* qkv_b   = (const float*)d_in[4];
    const float* proj_w  = (const float*)d_in[5];
    const float* proj_b  = (const float*)d_in[6];
    const float* rtab    = (const float*)d_in[7];
    const float* n2g     = (const float*)d_in[8];
    const float* n2b     = (const float*)d_in[9];
    const float* fc1_w   = (const float*)d_in[10];
    const float* fc1_b   = (const float*)d_in[11];
    const float* fc2_w   = (const float*)d_in[12];
    const float* fc2_b   = (const float*)d_in[13];
    float* out = (float*)d_out;

    char* wsb = (char*)d_ws;
    const size_t SZ = (size_t)T_TOT * C_DIM * 2;   // 77,070,336 bytes
    unsigned short* xwin = (unsigned short*)(wsb);
    unsigned short* qb   = (unsigned short*)(wsb + SZ);
    unsigned short* kb   = (unsigned short*)(wsb + 2*SZ);
    unsigned short* vb   = (unsigned short*)(wsb + 3*SZ);
    unsigned short* wt_qkv  = (unsigned short*)(wsb + 4*SZ);
    unsigned short* wt_proj = wt_qkv + 576*192;
    unsigned short* wt_fc1  = wt_proj + 192*192;
    unsigned short* wt_fc2  = wt_fc1 + 384*192;
    unsigned short* attn_o = xwin;   // reuse after QKV consumed xwin
    unsigned short* ln2  = qb;       // reuse after attention
    unsigned short* h1   = kb;       // spans kb+vb

    k_wprep<<<(192*576 + 255)/256, 256, 0, stream>>>(qkv_w, wt_qkv, 192, 576);
    k_wprep<<<(192*192 + 255)/256, 256, 0, stream>>>(proj_w, wt_proj, 192, 192);
    k_wprep<<<(192*384 + 255)/256, 256, 0, stream>>>(fc1_w, wt_fc1, 192, 384);
    k_wprep<<<(384*192 + 255)/256, 256, 0, stream>>>(fc2_w, wt_fc2, 384, 192);

    k_ln1_win<<<T_TOT/4, 256, 0, stream>>>(x, n1g, n1b, xwin);
    k_qkv_m<<<dim3(9, T_TOT/128), 256, 0, stream>>>(xwin, wt_qkv, qkv_b, qb, kb, vb);
    k_attn<<<NWIN*HEADS, 256, 0, stream>>>(qb, kb, vb, rtab, attn_o);
    k_proj_m<<<dim3(3, T_TOT/128), 256, 0, stream>>>(attn_o, wt_proj, proj_b, x, out);
    k_ln2<<<T_TOT/4, 256, 0, stream>>>(out, n2g, n2b, ln2);
    k_fc1_m<<<dim3(6, T_TOT/128), 256, 0, stream>>>(ln2, wt_fc1, fc1_b, h1);
    k_fc2_m<<<dim3(3, T_TOT/128), 256, 0, stream>>>(h1, wt_fc2, fc2_b, out);
}

// Round 6
// 862.059 us; speedup vs baseline: 2.4816x; 1.1291x over previous
//
#include <hip/hip_runtime.h>
#include <math.h>

#define T_TOT   200704
#define C_DIM   192
#define HEADS   6
#define DH      32
#define NTOK    64
#define NWIN    3136
#define HID     384
#define IMG     224
#define NSIDE   28
#define WPI     784
#define QSCALE  0.17677669529663687f

typedef unsigned short ushortT;
typedef short bf16x8 __attribute__((ext_vector_type(8)));
typedef float f32x4 __attribute__((ext_vector_type(4)));

__device__ __forceinline__ float bf_lo(unsigned u){ return __uint_as_float(u << 16); }
__device__ __forceinline__ float bf_hi(unsigned u){ return __uint_as_float(u & 0xFFFF0000u); }
__device__ __forceinline__ unsigned short f2bf(float f){
    unsigned u = __float_as_uint(f);
    u += 0x7FFFu + ((u >> 16) & 1u);
    return (unsigned short)(u >> 16);
}
__device__ __forceinline__ unsigned pack2(float a, float b){
    return (unsigned)f2bf(a) | ((unsigned)f2bf(b) << 16);
}

// ---------------- weight prep: out[n*K+k] = bf16(in[k*N+n])
__global__ void k_wprep(const float* __restrict__ w, unsigned short* __restrict__ o, int K, int N)
{
    int idx = blockIdx.x * 256 + threadIdx.x;
    if (idx >= K * N) return;
    int n = idx / K, k = idx - n * K;
    o[idx] = f2bf(w[(size_t)k * N + n]);
}

// ---------------- bias+mask prep: bmT[type][head][m][q] f32
__global__ void k_bmprep(const float* __restrict__ table, float* __restrict__ bmT)
{
    int idx = blockIdx.x * 256 + threadIdx.x;   // 4*6*64*64 = 98304
    int q = idx & 63, m = (idx >> 6) & 63;
    int head = (idx >> 12) % HEADS, type = idx / (64 * 64 * HEADS);
    int rq = q >> 3, cq = q & 7, rm = m >> 3, cm = m & 7;
    float b = table[((rq - rm + 7) * 15 + (cq - cm + 7)) * HEADS + head];
    int th = type >> 1, tw = type & 1;
    int lq = (th ? (rq >= 4 ? 2 : 1) : 0) * 3 + (tw ? (cq >= 4 ? 2 : 1) : 0);
    int lm = (th ? (rm >= 4 ? 2 : 1) : 0) * 3 + (tw ? (cm >= 4 ? 2 : 1) : 0);
    bmT[idx] = b + ((lq != lm) ? -100.f : 0.f);
}

// ---------------- K1: LN1 + shift + window partition -> xwin bf16 [t][192]
__global__ void k_ln1_win(const float* __restrict__ x, const float* __restrict__ g,
                          const float* __restrict__ bta, unsigned short* __restrict__ xwin)
{
    int t    = blockIdx.x * 4 + (threadIdx.x >> 6);
    int lane = threadIdx.x & 63;
    int win = t >> 6, n = t & 63;
    int bimg = win / WPI, w2 = win % WPI;
    int wi = w2 / NSIDE, wj = w2 % NSIDE;
    int r = n >> 3, c = n & 7;
    int hs = wi * 8 + r + 4; if (hs >= IMG) hs -= IMG;
    int ws = wj * 8 + c + 4; if (ws >= IMG) ws -= IMG;
    int s = bimg * (IMG*IMG) + hs * IMG + ws;
    const float* xp = x + (size_t)s * C_DIM + lane * 3;
    float v0 = xp[0], v1 = xp[1], v2 = xp[2];
    float sum = v0 + v1 + v2;
    float sq  = v0*v0 + v1*v1 + v2*v2;
    #pragma unroll
    for (int m = 1; m < 64; m <<= 1){ sum += __shfl_xor(sum, m); sq += __shfl_xor(sq, m); }
    float mu = sum * (1.f/192.f);
    float var = sq * (1.f/192.f) - mu*mu;
    float rs = rsqrtf(var + 1e-5f);
    int j = lane * 3;
    unsigned short* op = xwin + (size_t)t * C_DIM + j;
    op[0] = f2bf((v0-mu)*rs*g[j]   + bta[j]);
    op[1] = f2bf((v1-mu)*rs*g[j+1] + bta[j+1]);
    op[2] = f2bf((v2-mu)*rs*g[j+2] + bta[j+2]);
}

// ---------------- LN2 -> ln2 bf16 [t][192]
__global__ void k_ln2(const float* __restrict__ xin, const float* __restrict__ g,
                      const float* __restrict__ bta, unsigned short* __restrict__ o)
{
    int t    = blockIdx.x * 4 + (threadIdx.x >> 6);
    int lane = threadIdx.x & 63;
    const float* xp = xin + (size_t)t * C_DIM + lane * 3;
    float v0 = xp[0], v1 = xp[1], v2 = xp[2];
    float sum = v0 + v1 + v2;
    float sq  = v0*v0 + v1*v1 + v2*v2;
    #pragma unroll
    for (int m = 1; m < 64; m <<= 1){ sum += __shfl_xor(sum, m); sq += __shfl_xor(sq, m); }
    float mu = sum * (1.f/192.f);
    float var = sq * (1.f/192.f) - mu*mu;
    float rs = rsqrtf(var + 1e-5f);
    int j = lane * 3;
    unsigned short* op = o + (size_t)t * C_DIM + j;
    op[0] = f2bf((v0-mu)*rs*g[j]   + bta[j]);
    op[1] = f2bf((v1-mu)*rs*g[j+1] + bta[j+1]);
    op[2] = f2bf((v2-mu)*rs*g[j+2] + bta[j+2]);
}

// ---------------- MFMA GEMM tile: C[128x64] = A[128xK]bf16 @ Wt[NxK]^T bf16
template<int KTOT>
__device__ __forceinline__ void mfma_tile(const unsigned short* __restrict__ A,
                                          const unsigned short* __restrict__ Wt,
                                          int t0, int n0,
                                          f32x4 acc[4][2],
                                          unsigned short* As, unsigned short* Bs)
{
    const int tid = threadIdx.x;
    const int lane = tid & 63, wid = tid >> 6;
    const int wm = wid >> 1, wn = wid & 1;
    const int lr = lane & 15, lk = (lane >> 4) << 3;
    #pragma unroll
    for (int i = 0; i < 4; i++)
        #pragma unroll
        for (int j = 0; j < 2; j++)
            acc[i][j] = (f32x4){0.f, 0.f, 0.f, 0.f};

    const int arow = tid >> 1, asoff = (tid & 1) << 4;

    for (int k0 = 0; k0 < KTOT; k0 += 32){
        __syncthreads();
        {
            const unsigned short* ga = A + (size_t)(t0 + arow)*KTOT + k0 + asoff;
            *(uint4*)&As[arow*40 + asoff]     = *(const uint4*)(ga);
            *(uint4*)&As[arow*40 + asoff + 8] = *(const uint4*)(ga + 8);
            if (tid < 128){
                const unsigned short* gb = Wt + (size_t)(n0 + arow)*KTOT + k0 + asoff;
                *(uint4*)&Bs[arow*40 + asoff]     = *(const uint4*)(gb);
                *(uint4*)&Bs[arow*40 + asoff + 8] = *(const uint4*)(gb + 8);
            }
        }
        __syncthreads();
        bf16x8 b0 = *(const bf16x8*)&Bs[(wn*32 +      lr)*40 + lk];
        bf16x8 b1 = *(const bf16x8*)&Bs[(wn*32 + 16 + lr)*40 + lk];
        #pragma unroll
        for (int mf = 0; mf < 4; mf++){
            bf16x8 a = *(const bf16x8*)&As[(wm*64 + mf*16 + lr)*40 + lk];
            acc[mf][0] = __builtin_amdgcn_mfma_f32_16x16x32_bf16(a, b0, acc[mf][0], 0, 0, 0);
            acc[mf][1] = __builtin_amdgcn_mfma_f32_16x16x32_bf16(a, b1, acc[mf][1], 0, 0, 0);
        }
    }
}

// ---------------- K2: QKV GEMM -> q,k,v bf16 [win][head][64][32]
__global__ void k_qkv_m(const unsigned short* __restrict__ xwin, const unsigned short* __restrict__ wt,
                        const float* __restrict__ bias,
                        unsigned short* __restrict__ q, unsigned short* __restrict__ k,
                        unsigned short* __restrict__ v)
{
    __shared__ __align__(16) unsigned short As[128*40];
    __shared__ __align__(16) unsigned short Bs[64*40];
    int n0 = blockIdx.x * 64, t0 = blockIdx.y * 128;
    f32x4 acc[4][2];
    mfma_tile<C_DIM>(xwin, wt, t0, n0, acc, As, Bs);

    const int tid = threadIdx.x, lane = tid & 63, wid = tid >> 6;
    const int wm = wid >> 1, wn = wid & 1, lr = lane & 15;
    int win = blockIdx.y * 2 + wm;
    #pragma unroll
    for (int nf = 0; nf < 2; nf++){
        int c = n0 + wn*32 + nf*16 + lr;
        float b = bias[c];
        int which = c / C_DIM, cc = c % C_DIM;
        unsigned short* dst = (which == 0) ? q : (which == 1) ? k : v;
        float sc = (which == 0) ? QSCALE : 1.f;
        int head = cc >> 5, d = cc & 31;
        unsigned short* dp = dst + ((size_t)(win*HEADS + head) * NTOK) * DH + d;
        #pragma unroll
        for (int mf = 0; mf < 4; mf++){
            #pragma unroll
            for (int r = 0; r < 4; r++){
                int ntok = mf*16 + ((lane >> 4) << 2) + r;
                dp[ntok*DH] = f2bf((acc[mf][nf][r] + b) * sc);
            }
        }
    }
}

// ---------------- K3: MFMA windowed attention. 4 waves/block, 1 (win,head)/wave.
__global__ void k_attn_mfma(const unsigned short* __restrict__ q, const unsigned short* __restrict__ k,
                            const unsigned short* __restrict__ v, const float* __restrict__ bmT,
                            unsigned short* __restrict__ attn_o)
{
    __shared__ __align__(16) unsigned short Vt[4][32*72];
    __shared__ __align__(16) unsigned short Ps[4][64*72];
    const int tid = threadIdx.x, lane = tid & 63, wid = tid >> 6;
    const int wh = blockIdx.x * 4 + wid;
    const int head = wh % HEADS, win = wh / HEADS;
    const int w2 = win % WPI;
    const int type = ((w2 / NSIDE) == 27 ? 2 : 0) + ((w2 % NSIDE) == 27 ? 1 : 0);
    const size_t base = (size_t)wh * (NTOK * DH);
    const int lr = lane & 15, lg = lane >> 4;

    // ---- V transpose into LDS: Vt[d][tok], stride 72
    {
        const uint4* vp = (const uint4*)(v + base + lane * DH);
        uint4 va = vp[0], vb = vp[1], vc = vp[2], vd = vp[3];
        unsigned short* dst = &Vt[wid][lane];
        unsigned w0[8] = {va.x, va.y, va.z, va.w, vb.x, vb.y, vb.z, vb.w};
        #pragma unroll
        for (int j = 0; j < 8; j++){
            dst[(2*j)*72]   = (unsigned short)(w0[j] & 0xFFFFu);
            dst[(2*j+1)*72] = (unsigned short)(w0[j] >> 16);
        }
        unsigned w1[8] = {vc.x, vc.y, vc.z, vc.w, vd.x, vd.y, vd.z, vd.w};
        #pragma unroll
        for (int j = 0; j < 8; j++){
            dst[(16+2*j)*72]   = (unsigned short)(w1[j] & 0xFFFFu);
            dst[(16+2*j+1)*72] = (unsigned short)(w1[j] >> 16);
        }
    }

    // ---- Q/K fragments direct from global (layout [64][32] == fragment layout)
    bf16x8 aq[4], bk[4];
    {
        const unsigned short* qg = q + base + lr * DH + (lg << 3);
        const unsigned short* kg = k + base + lr * DH + (lg << 3);
        #pragma unroll
        for (int i = 0; i < 4; i++){
            aq[i] = *(const bf16x8*)(qg + i * 16 * DH);
            bk[i] = *(const bf16x8*)(kg + i * 16 * DH);
        }
    }

    // ---- S = Q K^T (16 MFMAs) + bias/mask
    f32x4 acc[4][4];
    #pragma unroll
    for (int mi = 0; mi < 4; mi++)
        #pragma unroll
        for (int ni = 0; ni < 4; ni++)
            acc[mi][ni] = __builtin_amdgcn_mfma_f32_16x16x32_bf16(aq[mi], bk[ni],
                              (f32x4){0.f,0.f,0.f,0.f}, 0, 0, 0);

    const float* bmBase = bmT + ((size_t)(type * HEADS + head) * 64) * 64;
    #pragma unroll
    for (int mi = 0; mi < 4; mi++)
        #pragma unroll
        for (int ni = 0; ni < 4; ni++){
            float4 bm = *(const float4*)(bmBase + (lr + 16*ni)*64 + lg*4 + 16*mi);
            acc[mi][ni][0] += bm.x; acc[mi][ni][1] += bm.y;
            acc[mi][ni][2] += bm.z; acc[mi][ni][3] += bm.w;
        }

    // ---- row softmax (rows live in (lg, r, mi); cols in (lr, ni)) -> Ps bf16
    #pragma unroll
    for (int mi = 0; mi < 4; mi++){
        #pragma unroll
        for (int r = 0; r < 4; r++){
            float mx = fmaxf(fmaxf(acc[mi][0][r], acc[mi][1][r]),
                             fmaxf(acc[mi][2][r], acc[mi][3][r]));
            mx = fmaxf(mx, __shfl_xor(mx, 1));
            mx = fmaxf(mx, __shfl_xor(mx, 2));
            mx = fmaxf(mx, __shfl_xor(mx, 4));
            mx = fmaxf(mx, __shfl_xor(mx, 8));
            float e0 = __expf(acc[mi][0][r] - mx);
            float e1 = __expf(acc[mi][1][r] - mx);
            float e2 = __expf(acc[mi][2][r] - mx);
            float e3 = __expf(acc[mi][3][r] - mx);
            float sum = e0 + e1 + e2 + e3;
            sum += __shfl_xor(sum, 1);
            sum += __shfl_xor(sum, 2);
            sum += __shfl_xor(sum, 4);
            sum += __shfl_xor(sum, 8);
            float inv = 1.f / sum;
            int row = lg*4 + r + 16*mi;
            unsigned short* pr = &Ps[wid][row*72 + lr];
            pr[0]  = f2bf(e0 * inv);
            pr[16] = f2bf(e1 * inv);
            pr[32] = f2bf(e2 * inv);
            pr[48] = f2bf(e3 * inv);
        }
    }

    // ---- out = P V (16 MFMAs)
    f32x4 o[4][2];
    #pragma unroll
    for (int mi = 0; mi < 4; mi++)
        #pragma unroll
        for (int ni = 0; ni < 2; ni++)
            o[mi][ni] = (f32x4){0.f,0.f,0.f,0.f};
    #pragma unroll
    for (int kb = 0; kb < 2; kb++){
        bf16x8 ap[4], bv[2];
        #pragma unroll
        for (int mi = 0; mi < 4; mi++)
            ap[mi] = *(const bf16x8*)&Ps[wid][(lr + 16*mi)*72 + (lg<<3) + 32*kb];
        #pragma unroll
        for (int ni = 0; ni < 2; ni++)
            bv[ni] = *(const bf16x8*)&Vt[wid][(lr + 16*ni)*72 + (lg<<3) + 32*kb];
        #pragma unroll
        for (int mi = 0; mi < 4; mi++)
            #pragma unroll
            for (int ni = 0; ni < 2; ni++)
                o[mi][ni] = __builtin_amdgcn_mfma_f32_16x16x32_bf16(ap[mi], bv[ni], o[mi][ni], 0, 0, 0);
    }

    // ---- store to attn_o [t][192]
    unsigned short* ob = attn_o + ((size_t)win * NTOK) * C_DIM + head * DH;
    #pragma unroll
    for (int mi = 0; mi < 4; mi++)
        #pragma unroll
        for (int ni = 0; ni < 2; ni++)
            #pragma unroll
            for (int r = 0; r < 4; r++){
                int row = lg*4 + r + 16*mi;
                ob[(size_t)row * C_DIM + lr + 16*ni] = f2bf(o[mi][ni][r]);
            }
}

// ---------------- K4: proj GEMM + un-window + un-shift + residual -> d_out f32
__global__ void k_proj_m(const unsigned short* __restrict__ ain, const unsigned short* __restrict__ wt,
                         const float* __restrict__ bias, const float* __restrict__ x,
                         float* __restrict__ out)
{
    __shared__ __align__(16) unsigned short As[128*40];
    __shared__ __align__(16) unsigned short Bs[64*40];
    int n0 = blockIdx.x * 64, t0 = blockIdx.y * 128;
    f32x4 acc[4][2];
    mfma_tile<C_DIM>(ain, wt, t0, n0, acc, As, Bs);

    const int tid = threadIdx.x, lane = tid & 63, wid = tid >> 6;
    const int wm = wid >> 1, wn = wid & 1, lr = lane & 15;
    float b0 = bias[n0 + wn*32 + lr];
    float b1 = bias[n0 + wn*32 + 16 + lr];
    #pragma unroll
    for (int mf = 0; mf < 4; mf++){
        #pragma unroll
        for (int r = 0; r < 4; r++){
            int t = t0 + wm*64 + mf*16 + ((lane >> 4) << 2) + r;
            int win = t >> 6, n = t & 63;
            int bimg = win / WPI, w2 = win % WPI;
            int wi = w2 / NSIDE, wj = w2 % NSIDE;
            int rr = n >> 3, cc = n & 7;
            int hf = wi*8 + rr + 4; if (hf >= IMG) hf -= IMG;
            int wf = wj*8 + cc + 4; if (wf >= IMG) wf -= IMG;
            size_t s = ((size_t)bimg*(IMG*IMG) + hf*IMG + wf) * C_DIM;
            int c0 = n0 + wn*32 + lr;
            out[s + c0]      = x[s + c0]      + acc[mf][0][r] + b0;
            out[s + c0 + 16] = x[s + c0 + 16] + acc[mf][1][r] + b1;
        }
    }
}

// ---------------- K6: fc1 GEMM + exact GELU -> h1 bf16 [t][384]
__global__ void k_fc1_m(const unsigned short* __restrict__ ain, const unsigned short* __restrict__ wt,
                        const float* __restrict__ bias, unsigned short* __restrict__ h1)
{
    __shared__ __align__(16) unsigned short As[128*40];
    __shared__ __align__(16) unsigned short Bs[64*40];
    int n0 = blockIdx.x * 64, t0 = blockIdx.y * 128;
    f32x4 acc[4][2];
    mfma_tile<C_DIM>(ain, wt, t0, n0, acc, As, Bs);

    const int tid = threadIdx.x, lane = tid & 63, wid = tid >> 6;
    const int wm = wid >> 1, wn = wid & 1, lr = lane & 15;
    #pragma unroll
    for (int nf = 0; nf < 2; nf++){
        int c = n0 + wn*32 + nf*16 + lr;
        float b = bias[c];
        #pragma unroll
        for (int mf = 0; mf < 4; mf++){
            #pragma unroll
            for (int r = 0; r < 4; r++){
                int t = t0 + wm*64 + mf*16 + ((lane >> 4) << 2) + r;
                float u = acc[mf][nf][r] + b;
                float gl = 0.5f*u*(1.f + erff(u*0.70710678118654752f));
                h1[(size_t)t*HID + c] = f2bf(gl);
            }
        }
    }
}

// ---------------- K7: fc2 GEMM + final residual add into d_out
__global__ void k_fc2_m(const unsigned short* __restrict__ ain, const unsigned short* __restrict__ wt,
                        const float* __restrict__ bias, float* __restrict__ out)
{
    __shared__ __align__(16) unsigned short As[128*40];
    __shared__ __align__(16) unsigned short Bs[64*40];
    int n0 = blockIdx.x * 64, t0 = blockIdx.y * 128;
    f32x4 acc[4][2];
    mfma_tile<HID>(ain, wt, t0, n0, acc, As, Bs);

    const int tid = threadIdx.x, lane = tid & 63, wid = tid >> 6;
    const int wm = wid >> 1, wn = wid & 1, lr = lane & 15;
    #pragma unroll
    for (int nf = 0; nf < 2; nf++){
        int c = n0 + wn*32 + nf*16 + lr;
        float b = bias[c];
        #pragma unroll
        for (int mf = 0; mf < 4; mf++){
            #pragma unroll
            for (int r = 0; r < 4; r++){
                int t = t0 + wm*64 + mf*16 + ((lane >> 4) << 2) + r;
                out[(size_t)t*C_DIM + c] += acc[mf][nf][r] + b;
            }
        }
    }
}

extern "C" void kernel_launch(void* const* d_in, const int* in_sizes, int n_in,
                              void* d_out, int out_size, void* d_ws, size_t ws_size,
                              hipStream_t stream)
{
    const float* x       = (const float*)d_in[0];
    const float* n1g     = (const float*)d_in[1];
    const float* n1b     = (const float*)d_in[2];
    const float* qkv_w   = (const float*)d_in[3];
    const float* qkv_b   = (const float*)d_in[4];
    const float* proj_w  = (const float*)d_in[5];
    const float* proj_b  = (const float*)d_in[6];
    const float* rtab    = (const float*)d_in[7];
    const float* n2g     = (const float*)d_in[8];
    const float* n2b     = (const float*)d_in[9];
    const float* fc1_w   = (const float*)d_in[10];
    const float* fc1_b   = (const float*)d_in[11];
    const float* fc2_w   = (const float*)d_in[12];
    const float* fc2_b   = (const float*)d_in[13];
    float* out = (float*)d_out;

    char* wsb = (char*)d_ws;
    const size_t SZ = (size_t)T_TOT * C_DIM * 2;   // 77,070,336 bytes
    unsigned short* xwin = (unsigned short*)(wsb);
    unsigned short* qb   = (unsigned short*)(wsb + SZ);
    unsigned short* kb   = (unsigned short*)(wsb + 2*SZ);
    unsigned short* vb   = (unsigned short*)(wsb + 3*SZ);
    unsigned short* wt_qkv  = (unsigned short*)(wsb + 4*SZ);
    unsigned short* wt_proj = wt_qkv + 576*192;
    unsigned short* wt_fc1  = wt_proj + 192*192;
    unsigned short* wt_fc2  = wt_fc1 + 384*192;
    float*          bmT     = (float*)(wt_fc2 + 384*192);   // 4*6*64*64 f32
    unsigned short* attn_o = xwin;   // reuse after QKV consumed xwin
    unsigned short* ln2  = qb;       // reuse after attention
    unsigned short* h1   = kb;       // spans kb+vb

    k_wprep<<<(192*576 + 255)/256, 256, 0, stream>>>(qkv_w, wt_qkv, 192, 576);
    k_wprep<<<(192*192 + 255)/256, 256, 0, stream>>>(proj_w, wt_proj, 192, 192);
    k_wprep<<<(192*384 + 255)/256, 256, 0, stream>>>(fc1_w, wt_fc1, 192, 384);
    k_wprep<<<(384*192 + 255)/256, 256, 0, stream>>>(fc2_w, wt_fc2, 384, 192);
    k_bmprep<<<(4*HEADS*64*64)/256, 256, 0, stream>>>(rtab, bmT);

    k_ln1_win<<<T_TOT/4, 256, 0, stream>>>(x, n1g, n1b, xwin);
    k_qkv_m<<<dim3(9, T_TOT/128), 256, 0, stream>>>(xwin, wt_qkv, qkv_b, qb, kb, vb);
    k_attn_mfma<<<NWIN*HEADS/4, 256, 0, stream>>>(qb, kb, vb, bmT, attn_o);
    k_proj_m<<<dim3(3, T_TOT/128), 256, 0, stream>>>(attn_o, wt_proj, proj_b, x, out);
    k_ln2<<<T_TOT/4, 256, 0, stream>>>(out, n2g, n2b, ln2);
    k_fc1_m<<<dim3(6, T_TOT/128), 256, 0, stream>>>(ln2, wt_fc1, fc1_b, h1);
    k_fc2_m<<<dim3(3, T_TOT/128), 256, 0, stream>>>(h1, wt_fc2, fc2_b, out);
}